// Round 9
// baseline (45.712 us; speedup 1.0000x reference)
//
#include <hip/hip_runtime.h>
#include <cstdint>
#include <cstddef>

// ---------------------------------------------------------------------------
// DeepIM: VAE (matvec chain) + 2-layer GAT on 1%-dense adjacency.
//  - GAT heads are rank-1 => logits e[i,j]=leaky(c1*xh[i]+c2*xh[j]); head
//    outputs collapse to scalars. No NxN / Nx64 intermediates.
//  - adjacency (int32 words) -> per-row CSR (u16 cols, ~41/row), scanned in
//    one wave iteration per GAT row.
//  - R9: csrRow preloads all 16 uint4 into registers BEFORE ballot-processing
//    (R5/R7 failure root-cause: load->ballot per-iter serialization kept
//    per-block conv at ~16GB/s). With that fixed, a BOUNDED taper moves
//    768 adjacency rows onto enc2 (64 blocks) and dec3 (128 blocks), conv
//    blocks FIRST; mega keeps 3328 rows. Stream order still guarantees CSR
//    complete before gat_heads.
//  - R3/R4 lesson: no device-scope spin barriers (~70us each at 512 blocks).
//  - R5/R7 lesson: side-work must not extend its host stage; slices sized to
//    stage slack, only on the two longest mid stages.
// ---------------------------------------------------------------------------

typedef unsigned long long u64;

#define ACT_RELU 1
#define ACT_SIG  2

__device__ __forceinline__ float d4(float4 a, float4 b) {
  return a.x * b.x + a.y * b.y + a.z * b.z + a.w * b.w;
}
__device__ __forceinline__ float waveRed(float v) {
  for (int o = 32; o; o >>= 1) v += __shfl_down(v, o);
  return v;  // lane 0 holds sum
}

// conv: one adjacency row (4096 int32 words) -> sorted CSR.
// Phase 1: preload all 16 uint4 (64 VGPRs) so the 16 loads pipeline;
// Phase 2: ballot/popcount compaction on register-resident data.
// Element e = it*64+lane covers cols it*256+4*lane .. +3.
__device__ __forceinline__ void csrRow(const uint4* aw, unsigned short* edges,
                                       unsigned* cnt, int r, int lane) {
  const uint4* rp = aw + (size_t)r * 1024u;
  unsigned short* er = edges + (size_t)r * 1024u;
  uint4 v[16];
#pragma unroll
  for (int it = 0; it < 16; ++it) v[it] = rp[it * 64 + lane];

  const u64 pmb = ((~0ull) >> (63 - lane)) >> 1;  // bits [0,lane)
  unsigned total = 0;
#pragma unroll
  for (int it = 0; it < 16; ++it) {
    const int colb = it * 256 + 4 * lane;
    u64 m;
    m = __ballot(v[it].x != 0u);
    if (v[it].x) er[min(total + (unsigned)__popcll(m & pmb), 1023u)] = (unsigned short)colb;
    total += (unsigned)__popcll(m);
    m = __ballot(v[it].y != 0u);
    if (v[it].y) er[min(total + (unsigned)__popcll(m & pmb), 1023u)] = (unsigned short)(colb + 1);
    total += (unsigned)__popcll(m);
    m = __ballot(v[it].z != 0u);
    if (v[it].z) er[min(total + (unsigned)__popcll(m & pmb), 1023u)] = (unsigned short)(colb + 2);
    total += (unsigned)__popcll(m);
    m = __ballot(v[it].w != 0u);
    if (v[it].w) er[min(total + (unsigned)__popcll(m & pmb), 1023u)] = (unsigned short)(colb + 3);
    total += (unsigned)__popcll(m);
  }
  if (lane == 0) cnt[r] = min(total, 1024u);
}

// Conv side-work at LOW blockIdx: blocks [0,CB) convert rows
// [convBase, convBase+CB*4). Returns true if this block was a conv block.
__device__ __forceinline__ bool convFirst(int CB, int convBase, const void* adj,
                                          unsigned short* edges, unsigned* cnt) {
  if ((int)blockIdx.x >= CB) return false;
  const int row = convBase + blockIdx.x * 4 + (threadIdx.x >> 6);
  csrRow((const uint4*)adj, edges, cnt, row, threadIdx.x & 63);
  return true;
}

// Mega dispatch #1: [0,832) conv rows [0,3328); [832,1856) enc1; 1856 prep.
struct MegaP {
  const void* adj;
  unsigned short* edges;
  unsigned* cnt;
  const float *w1, *x, *b1;
  float* h1;
  const float *gw, *ga, *ow, *oa;
  float* consts;  // [c1(4), c2(4), d(4), oa0, oa1]
};

__global__ __launch_bounds__(256) void mega_kernel(MegaP p) {
  const int tid = threadIdx.x, w = tid >> 6, lane = tid & 63;
  const int blk = blockIdx.x;
  if (blk < 832) {                         // ---- conv rows blk*4+w in [0,3328)
    csrRow((const uint4*)p.adj, p.edges, p.cnt, blk * 4 + w, lane);
    return;
  }
  if (blk < 1856) {                        // ---- enc1 row
    const int r = blk - 832;
    const float4* row = (const float4*)(p.w1 + (size_t)r * 4096u);
    const float4* x4 = (const float4*)p.x;
    float acc = 0.f;
#pragma unroll
    for (int k = 0; k < 4; ++k) {
      const int idx = tid + 256 * k;
      acc += d4(row[idx], x4[idx]);
    }
    acc = waveRed(acc);
    __shared__ float lds[4];
    if (lane == 0) lds[w] = acc;
    __syncthreads();
    if (tid == 0) {
      const float v = lds[0] + lds[1] + lds[2] + lds[3] + p.b1[r];
      p.h1[r] = v > 0.f ? v : 0.f;
    }
    return;
  }
  // ---- prep: per-head scalars (1 block)
  const int h = w, k = lane;
  const float wv = p.gw[h * 64 + k];
  float p1 = wv * p.ga[h * 128 + k];
  float p2 = wv * p.ga[h * 128 + 64 + k];
  float p3 = wv * p.ow[h * 64 + k];
  for (int off = 32; off; off >>= 1) {
    p1 += __shfl_down(p1, off);
    p2 += __shfl_down(p2, off);
    p3 += __shfl_down(p3, off);
  }
  if (k == 0) { p.consts[h] = p1; p.consts[4 + h] = p2; p.consts[8 + h] = p3; }
  if (tid == 0) { p.consts[12] = p.oa[0]; p.consts[13] = p.oa[1]; }
}

// y[r]=act(dot(W[r,:],x)+b[r]); optional conv slice at blocks [0,CB).
template<int ACT>
__global__ __launch_bounds__(256) void mv_conv_kernel(const float* __restrict__ W,
    const float* __restrict__ x, const float* __restrict__ b,
    float* __restrict__ y, int C, int CB, int convBase,
    const void* __restrict__ adj, unsigned short* __restrict__ edges,
    unsigned* __restrict__ cnt) {
  if (CB && convFirst(CB, convBase, adj, edges, cnt)) return;
  const int r = blockIdx.x - CB;
  const float* row = W + (size_t)r * (size_t)C;
  float acc = 0.f;
  for (int c = threadIdx.x * 4; c < C; c += 256 * 4) {
    const float4 w4 = *reinterpret_cast<const float4*>(row + c);
    const float4 x4 = *reinterpret_cast<const float4*>(x + c);
    acc += d4(w4, x4);
  }
  acc = waveRed(acc);
  __shared__ float lds[4];
  if ((threadIdx.x & 63) == 0) lds[threadIdx.x >> 6] = acc;
  __syncthreads();
  if (threadIdx.x == 0) {
    float v = lds[0] + lds[1] + lds[2] + lds[3] + b[r];
    if (ACT == ACT_RELU) v = v > 0.f ? v : 0.f;
    if (ACT == ACT_SIG)  v = 1.f / (1.f + expf(-v));
    y[r] = v;
  }
}

// mu (rows 0..511 via w3) and logvar (rows 512..1023 via w4) in one grid.
__global__ __launch_bounds__(256) void mulv_kernel(const float* __restrict__ w3,
    const float* __restrict__ b3, const float* __restrict__ w4,
    const float* __restrict__ b4, const float* __restrict__ h2,
    float* __restrict__ mu, float* __restrict__ logvar) {
  const int r = blockIdx.x;
  const bool is_mu = r < 512;
  const int rr = is_mu ? r : r - 512;
  const float* row = (is_mu ? w3 : w4) + (size_t)rr * 1024u;
  const int c = threadIdx.x * 4;
  float acc = d4(*reinterpret_cast<const float4*>(row + c),
                 *reinterpret_cast<const float4*>(h2 + c));
  acc = waveRed(acc);
  __shared__ float lds[4];
  if ((threadIdx.x & 63) == 0) lds[threadIdx.x >> 6] = acc;
  __syncthreads();
  if (threadIdx.x == 0) {
    const float v = lds[0] + lds[1] + lds[2] + lds[3] + (is_mu ? b3[rr] : b4[rr]);
    (is_mu ? mu : logvar)[rr] = v;
  }
}

// dec1 with z = mu + eps*exp(0.5*logvar) computed in LDS per block.
__global__ __launch_bounds__(256) void dec1_kernel(const float* __restrict__ W,
    const float* __restrict__ mu, const float* __restrict__ logvar,
    const float* __restrict__ eps, const float* __restrict__ b,
    float* __restrict__ y) {
  __shared__ float zsh[512];
  for (int k = threadIdx.x; k < 512; k += 256)
    zsh[k] = mu[k] + eps[k] * expf(0.5f * logvar[k]);
  __syncthreads();
  const int r = blockIdx.x;
  const float* row = W + (size_t)r * 512u;
  const int c = threadIdx.x * 2;
  const float2 w2 = *reinterpret_cast<const float2*>(row + c);
  float acc = w2.x * zsh[c] + w2.y * zsh[c + 1];
  acc = waveRed(acc);
  __shared__ float lds[4];
  if ((threadIdx.x & 63) == 0) lds[threadIdx.x >> 6] = acc;
  __syncthreads();
  if (threadIdx.x == 0) {
    float v = lds[0] + lds[1] + lds[2] + lds[3] + b[r];
    y[r] = v > 0.f ? v : 0.f;
  }
}

// 4 heads fused, CSR scan. One wave per row; lane j handles edge j.
__global__ __launch_bounds__(256) void gat_heads_csr(
    const unsigned short* __restrict__ edges, const unsigned* __restrict__ cnt,
    const float* __restrict__ xh, const float* __restrict__ consts,
    float* __restrict__ wh2) {
  const int lane = threadIdx.x & 63;
  const int i = blockIdx.x * 4 + (threadIdx.x >> 6);
  const unsigned n = cnt[i];
  const float xi = xh[i];
  const float A0 = consts[0] * xi, A1 = consts[1] * xi,
              A2 = consts[2] * xi, A3 = consts[3] * xi;
  const float c20 = consts[4], c21 = consts[5], c22 = consts[6], c23 = consts[7];
  float s0 = 0, s1 = 0, s2 = 0, s3 = 0, t0 = 0, t1 = 0, t2 = 0, t3 = 0;
  const unsigned short* er = edges + (size_t)i * 1024u;
  for (unsigned j = lane; j < n; j += 64) {
    const float xj = xh[er[j]];
    float e0 = A0 + c20 * xj, e1 = A1 + c21 * xj, e2 = A2 + c22 * xj, e3 = A3 + c23 * xj;
    e0 = fmaxf(e0, 0.2f * e0); e1 = fmaxf(e1, 0.2f * e1);
    e2 = fmaxf(e2, 0.2f * e2); e3 = fmaxf(e3, 0.2f * e3);
    const float w0 = expf(e0), w1 = expf(e1), w2 = expf(e2), w3 = expf(e3);
    s0 += w0; s1 += w1; s2 += w2; s3 += w3;
    t0 += w0 * xj; t1 += w1 * xj; t2 += w2 * xj; t3 += w3 * xj;
  }
  for (int o = 1; o < 64; o <<= 1) {
    s0 += __shfl_xor(s0, o); s1 += __shfl_xor(s1, o);
    s2 += __shfl_xor(s2, o); s3 += __shfl_xor(s3, o);
    t0 += __shfl_xor(t0, o); t1 += __shfl_xor(t1, o);
    t2 += __shfl_xor(t2, o); t3 += __shfl_xor(t3, o);
  }
  float r0, r1, r2, r3;
  if (n != 0) { r0 = t0 / s0; r1 = t1 / s1; r2 = t2 / s2; r3 = t3 / s3; }
  else {  // empty row -> uniform attention (mean of xh)
    float a = 0.f;
    for (int k = lane; k < 4096; k += 64) a += xh[k];
    for (int o = 1; o < 64; o <<= 1) a += __shfl_xor(a, o);
    r0 = r1 = r2 = r3 = a * (1.f / 4096.f);
  }
  if (lane == 0)
    wh2[i] = consts[8] * r0 + consts[9] * r1 + consts[10] * r2 + consts[11] * r3;
}

// Output GAT layer (f=1), CSR scan. y = elu(att @ Wh2).
__global__ __launch_bounds__(256) void gat_out_csr(
    const unsigned short* __restrict__ edges, const unsigned* __restrict__ cnt,
    const float* __restrict__ wh2, const float* __restrict__ consts,
    float* __restrict__ yhat) {
  const int lane = threadIdx.x & 63;
  const int i = blockIdx.x * 4 + (threadIdx.x >> 6);
  const unsigned n = cnt[i];
  const float Ai = consts[12] * wh2[i];
  const float oa1 = consts[13];
  float s = 0.f, t = 0.f;
  const unsigned short* er = edges + (size_t)i * 1024u;
  for (unsigned j = lane; j < n; j += 64) {
    const float wj = wh2[er[j]];
    float e = Ai + oa1 * wj;
    e = fmaxf(e, 0.2f * e);
    const float ww = expf(e);
    s += ww; t += ww * wj;
  }
  for (int o = 1; o < 64; o <<= 1) {
    s += __shfl_xor(s, o);
    t += __shfl_xor(t, o);
  }
  float v;
  if (n != 0) v = t / s;
  else {
    float a = 0.f;
    for (int k = lane; k < 4096; k += 64) a += wh2[k];
    for (int o = 1; o < 64; o <<= 1) a += __shfl_xor(a, o);
    v = a * (1.f / 4096.f);
  }
  if (lane == 0) yhat[i] = v > 0.f ? v : expm1f(v);
}

extern "C" void kernel_launch(void* const* d_in, const int* in_sizes, int n_in,
                              void* d_out, int out_size, void* d_ws, size_t ws_size,
                              hipStream_t stream) {
  const float* x      = (const float*)d_in[0];
  const float* eps    = (const float*)d_in[1];
  const void*  adj    = d_in[2];
  const float* enc_w1 = (const float*)d_in[3];
  const float* enc_b1 = (const float*)d_in[4];
  const float* enc_w2 = (const float*)d_in[5];
  const float* enc_b2 = (const float*)d_in[6];
  const float* enc_w3 = (const float*)d_in[7];
  const float* enc_b3 = (const float*)d_in[8];
  const float* enc_w4 = (const float*)d_in[9];
  const float* enc_b4 = (const float*)d_in[10];
  const float* dec_w1 = (const float*)d_in[11];
  const float* dec_b1 = (const float*)d_in[12];
  const float* dec_w2 = (const float*)d_in[13];
  const float* dec_b2 = (const float*)d_in[14];
  const float* dec_w3 = (const float*)d_in[15];
  const float* dec_b3 = (const float*)d_in[16];
  const float* gat_W  = (const float*)d_in[17];
  const float* gat_a  = (const float*)d_in[18];
  const float* out_W  = (const float*)d_in[19];
  const float* out_a  = (const float*)d_in[20];

  float* out    = (float*)d_out;
  float* xhat   = out;          // [0,4096)
  float* yhat   = out + 4096;   // [4096,8192)
  float* mu     = out + 8192;   // [8192,8704)
  float* logvar = out + 8704;   // [8704,9216)

  // ws layout: edges 8MB | cnt 16KB | float scratch
  unsigned short* edges = (unsigned short*)d_ws;
  unsigned* cnt = (unsigned*)((char*)d_ws + (size_t)4096 * 1024 * 2);
  float* F      = (float*)((char*)cnt + 4096 * sizeof(unsigned));
  float* h1     = F;            // 1024
  float* h2     = F + 1024;     // 1024
  float* h3     = F + 2048;     // 1024
  float* h4     = F + 3072;     // 1024
  float* wh2    = F + 4096;     // 4096
  float* consts = F + 8208;     // 14

  // Dispatch 1: conv rows [0,3328) (832 blocks) + enc1 (1024) + prep (1).
  MegaP mp;
  mp.adj = adj; mp.edges = edges; mp.cnt = cnt;
  mp.w1 = enc_w1; mp.x = x; mp.b1 = enc_b1; mp.h1 = h1;
  mp.gw = gat_W; mp.ga = gat_a; mp.ow = out_W; mp.oa = out_a;
  mp.consts = consts;
  mega_kernel<<<1857, 256, 0, stream>>>(mp);

  // VAE chain. Bounded conv slices only on the two longest mid stages:
  // enc2 carries rows [3328,3584) (64 blocks); dec3 carries [3584,4096) (128).
  mv_conv_kernel<ACT_RELU><<<64 + 1024, 256, 0, stream>>>(
      enc_w2, h1, enc_b2, h2, 1024, 64, 3328, adj, edges, cnt);
  mulv_kernel<<<1024, 256, 0, stream>>>(enc_w3, enc_b3, enc_w4, enc_b4, h2, mu, logvar);
  dec1_kernel<<<1024, 256, 0, stream>>>(dec_w1, mu, logvar, eps, dec_b1, h3);
  mv_conv_kernel<ACT_RELU><<<1024, 256, 0, stream>>>(
      dec_w2, h3, dec_b2, h4, 1024, 0, 0, adj, edges, cnt);
  mv_conv_kernel<ACT_SIG><<<128 + 4096, 256, 0, stream>>>(
      dec_w3, h4, dec_b3, xhat, 1024, 128, 3584, adj, edges, cnt);

  // GAT (CSR + consts complete by stream order).
  gat_heads_csr<<<1024, 256, 0, stream>>>(edges, cnt, xhat, consts, wh2);
  gat_out_csr<<<1024, 256, 0, stream>>>(edges, cnt, wh2, consts, yhat);
}

// Round 10
// 43.076 us; speedup vs baseline: 1.0612x; 1.0612x over previous
//
#include <hip/hip_runtime.h>
#include <cstdint>
#include <cstddef>

// ---------------------------------------------------------------------------
// DeepIM: VAE (matvec chain) + 2-layer GAT on 1%-dense adjacency.
//  - GAT heads are rank-1 => logits e[i,j]=leaky(c1*xh[i]+c2*xh[j]); head
//    outputs collapse to scalars. No NxN / Nx64 intermediates.
//  - adjacency (int32 words) -> per-row CSR (u16 cols, ~41/row), scanned in
//    one wave iteration per GAT row. CSR reads/writes touch only ~41
//    entries/row, so GAT traffic is ~300KB (L2-resident).
//  - R10 = R8 structure (proven best, 43.0us): 8 dispatches, ALL conv in the
//    mega dispatch (1024 blocks FIRST) + enc1 (1024) + prep (1). csrRow uses
//    R9's register-preload (16 uint4 in flight before ballot processing).
//  - R3/R4 lesson: no device-scope spin barriers (~70us each at 512 blocks);
//    dispatch boundaries are the cheap sync.
//  - R5/R7/R9 lesson (thrice-burned): NEVER taper conv onto short stages —
//    a conv block's ~1-2us lifetime exceeds mid-stage totals; conv hides
//    only inside mega's 13us adjacency pole.
//  - Structural floor ~38-40us: mega 13.2 (BW), 4 mid stages launch-bound
//    ~2us each, dec3 ~3, GAT pair ~5, ~7 gaps. At ~43 we're done.
// ---------------------------------------------------------------------------

typedef unsigned long long u64;

#define ACT_RELU 1
#define ACT_SIG  2

__device__ __forceinline__ float d4(float4 a, float4 b) {
  return a.x * b.x + a.y * b.y + a.z * b.z + a.w * b.w;
}
__device__ __forceinline__ float waveRed(float v) {
  for (int o = 32; o; o >>= 1) v += __shfl_down(v, o);
  return v;  // lane 0 holds sum
}

// conv: one adjacency row (4096 int32 words) -> sorted CSR.
// Phase 1: preload all 16 uint4 so the loads pipeline (one waitcnt, not 16);
// Phase 2: ballot/popcount compaction on register-resident data.
// Element e = it*64+lane covers cols it*256+4*lane .. +3.
__device__ __forceinline__ void csrRow(const uint4* aw, unsigned short* edges,
                                       unsigned* cnt, int r, int lane) {
  const uint4* rp = aw + (size_t)r * 1024u;
  unsigned short* er = edges + (size_t)r * 1024u;
  uint4 v[16];
#pragma unroll
  for (int it = 0; it < 16; ++it) v[it] = rp[it * 64 + lane];

  const u64 pmb = ((~0ull) >> (63 - lane)) >> 1;  // bits [0,lane)
  unsigned total = 0;
#pragma unroll
  for (int it = 0; it < 16; ++it) {
    const int colb = it * 256 + 4 * lane;
    u64 m;
    m = __ballot(v[it].x != 0u);
    if (v[it].x) er[min(total + (unsigned)__popcll(m & pmb), 1023u)] = (unsigned short)colb;
    total += (unsigned)__popcll(m);
    m = __ballot(v[it].y != 0u);
    if (v[it].y) er[min(total + (unsigned)__popcll(m & pmb), 1023u)] = (unsigned short)(colb + 1);
    total += (unsigned)__popcll(m);
    m = __ballot(v[it].z != 0u);
    if (v[it].z) er[min(total + (unsigned)__popcll(m & pmb), 1023u)] = (unsigned short)(colb + 2);
    total += (unsigned)__popcll(m);
    m = __ballot(v[it].w != 0u);
    if (v[it].w) er[min(total + (unsigned)__popcll(m & pmb), 1023u)] = (unsigned short)(colb + 3);
    total += (unsigned)__popcll(m);
  }
  if (lane == 0) cnt[r] = min(total, 1024u);
}

// Mega dispatch #1: [0,1024) conv->CSR (4 rows/block, 1 row/wave);
// [1024,2048) enc1 rows; block 2048: GAT prep scalars. All independent.
struct MegaP {
  const void* adj;
  unsigned short* edges;
  unsigned* cnt;
  const float *w1, *x, *b1;
  float* h1;
  const float *gw, *ga, *ow, *oa;
  float* consts;  // [c1(4), c2(4), d(4), oa0, oa1]
};

__global__ __launch_bounds__(256) void mega_kernel(MegaP p) {
  const int tid = threadIdx.x, w = tid >> 6, lane = tid & 63;
  const int blk = blockIdx.x;
  if (blk < 1024) {                        // ---- conv rows blk*4+w
    csrRow((const uint4*)p.adj, p.edges, p.cnt, blk * 4 + w, lane);
    return;
  }
  if (blk < 2048) {                        // ---- enc1 row
    const int r = blk - 1024;
    const float4* row = (const float4*)(p.w1 + (size_t)r * 4096u);
    const float4* x4 = (const float4*)p.x;
    float acc = 0.f;
#pragma unroll
    for (int k = 0; k < 4; ++k) {
      const int idx = tid + 256 * k;
      acc += d4(row[idx], x4[idx]);
    }
    acc = waveRed(acc);
    __shared__ float lds[4];
    if (lane == 0) lds[w] = acc;
    __syncthreads();
    if (tid == 0) {
      const float v = lds[0] + lds[1] + lds[2] + lds[3] + p.b1[r];
      p.h1[r] = v > 0.f ? v : 0.f;
    }
    return;
  }
  // ---- prep: per-head scalars (1 block)
  const int h = w, k = lane;
  const float wv = p.gw[h * 64 + k];
  float p1 = wv * p.ga[h * 128 + k];
  float p2 = wv * p.ga[h * 128 + 64 + k];
  float p3 = wv * p.ow[h * 64 + k];
  for (int off = 32; off; off >>= 1) {
    p1 += __shfl_down(p1, off);
    p2 += __shfl_down(p2, off);
    p3 += __shfl_down(p3, off);
  }
  if (k == 0) { p.consts[h] = p1; p.consts[4 + h] = p2; p.consts[8 + h] = p3; }
  if (tid == 0) { p.consts[12] = p.oa[0]; p.consts[13] = p.oa[1]; }
}

// y[r] = act( dot(W[r,:], x) + b[r] );  one block (256 thr) per row.
template<int ACT>
__global__ __launch_bounds__(256) void mv_kernel(const float* __restrict__ W,
    const float* __restrict__ x, const float* __restrict__ b,
    float* __restrict__ y, int C) {
  const int r = blockIdx.x;
  const float* row = W + (size_t)r * (size_t)C;
  float acc = 0.f;
  for (int c = threadIdx.x * 4; c < C; c += 256 * 4) {
    const float4 w4 = *reinterpret_cast<const float4*>(row + c);
    const float4 x4 = *reinterpret_cast<const float4*>(x + c);
    acc += d4(w4, x4);
  }
  acc = waveRed(acc);
  __shared__ float lds[4];
  if ((threadIdx.x & 63) == 0) lds[threadIdx.x >> 6] = acc;
  __syncthreads();
  if (threadIdx.x == 0) {
    float v = lds[0] + lds[1] + lds[2] + lds[3] + b[r];
    if (ACT == ACT_RELU) v = v > 0.f ? v : 0.f;
    if (ACT == ACT_SIG)  v = 1.f / (1.f + expf(-v));
    y[r] = v;
  }
}

// mu (rows 0..511 via w3) and logvar (rows 512..1023 via w4) in one grid.
__global__ __launch_bounds__(256) void mulv_kernel(const float* __restrict__ w3,
    const float* __restrict__ b3, const float* __restrict__ w4,
    const float* __restrict__ b4, const float* __restrict__ h2,
    float* __restrict__ mu, float* __restrict__ logvar) {
  const int r = blockIdx.x;
  const bool is_mu = r < 512;
  const int rr = is_mu ? r : r - 512;
  const float* row = (is_mu ? w3 : w4) + (size_t)rr * 1024u;
  const int c = threadIdx.x * 4;
  float acc = d4(*reinterpret_cast<const float4*>(row + c),
                 *reinterpret_cast<const float4*>(h2 + c));
  acc = waveRed(acc);
  __shared__ float lds[4];
  if ((threadIdx.x & 63) == 0) lds[threadIdx.x >> 6] = acc;
  __syncthreads();
  if (threadIdx.x == 0) {
    const float v = lds[0] + lds[1] + lds[2] + lds[3] + (is_mu ? b3[rr] : b4[rr]);
    (is_mu ? mu : logvar)[rr] = v;
  }
}

// dec1 with z = mu + eps*exp(0.5*logvar) computed in LDS per block.
__global__ __launch_bounds__(256) void dec1_kernel(const float* __restrict__ W,
    const float* __restrict__ mu, const float* __restrict__ logvar,
    const float* __restrict__ eps, const float* __restrict__ b,
    float* __restrict__ y) {
  __shared__ float zsh[512];
  for (int k = threadIdx.x; k < 512; k += 256)
    zsh[k] = mu[k] + eps[k] * expf(0.5f * logvar[k]);
  __syncthreads();
  const int r = blockIdx.x;
  const float* row = W + (size_t)r * 512u;
  const int c = threadIdx.x * 2;
  const float2 w2 = *reinterpret_cast<const float2*>(row + c);
  float acc = w2.x * zsh[c] + w2.y * zsh[c + 1];
  acc = waveRed(acc);
  __shared__ float lds[4];
  if ((threadIdx.x & 63) == 0) lds[threadIdx.x >> 6] = acc;
  __syncthreads();
  if (threadIdx.x == 0) {
    float v = lds[0] + lds[1] + lds[2] + lds[3] + b[r];
    y[r] = v > 0.f ? v : 0.f;
  }
}

// 4 heads fused, CSR scan. One wave per row; lane j handles edge j
// (typical degree ~41 < 64 -> single iteration).
__global__ __launch_bounds__(256) void gat_heads_csr(
    const unsigned short* __restrict__ edges, const unsigned* __restrict__ cnt,
    const float* __restrict__ xh, const float* __restrict__ consts,
    float* __restrict__ wh2) {
  const int lane = threadIdx.x & 63;
  const int i = blockIdx.x * 4 + (threadIdx.x >> 6);
  const unsigned n = cnt[i];
  const float xi = xh[i];
  const float A0 = consts[0] * xi, A1 = consts[1] * xi,
              A2 = consts[2] * xi, A3 = consts[3] * xi;
  const float c20 = consts[4], c21 = consts[5], c22 = consts[6], c23 = consts[7];
  float s0 = 0, s1 = 0, s2 = 0, s3 = 0, t0 = 0, t1 = 0, t2 = 0, t3 = 0;
  const unsigned short* er = edges + (size_t)i * 1024u;
  for (unsigned j = lane; j < n; j += 64) {
    const float xj = xh[er[j]];
    float e0 = A0 + c20 * xj, e1 = A1 + c21 * xj, e2 = A2 + c22 * xj, e3 = A3 + c23 * xj;
    e0 = fmaxf(e0, 0.2f * e0); e1 = fmaxf(e1, 0.2f * e1);
    e2 = fmaxf(e2, 0.2f * e2); e3 = fmaxf(e3, 0.2f * e3);
    const float w0 = expf(e0), w1 = expf(e1), w2 = expf(e2), w3 = expf(e3);
    s0 += w0; s1 += w1; s2 += w2; s3 += w3;
    t0 += w0 * xj; t1 += w1 * xj; t2 += w2 * xj; t3 += w3 * xj;
  }
  for (int o = 1; o < 64; o <<= 1) {
    s0 += __shfl_xor(s0, o); s1 += __shfl_xor(s1, o);
    s2 += __shfl_xor(s2, o); s3 += __shfl_xor(s3, o);
    t0 += __shfl_xor(t0, o); t1 += __shfl_xor(t1, o);
    t2 += __shfl_xor(t2, o); t3 += __shfl_xor(t3, o);
  }
  float r0, r1, r2, r3;
  if (n != 0) { r0 = t0 / s0; r1 = t1 / s1; r2 = t2 / s2; r3 = t3 / s3; }
  else {  // empty row -> uniform attention (mean of xh)
    float a = 0.f;
    for (int k = lane; k < 4096; k += 64) a += xh[k];
    for (int o = 1; o < 64; o <<= 1) a += __shfl_xor(a, o);
    r0 = r1 = r2 = r3 = a * (1.f / 4096.f);
  }
  if (lane == 0)
    wh2[i] = consts[8] * r0 + consts[9] * r1 + consts[10] * r2 + consts[11] * r3;
}

// Output GAT layer (f=1), CSR scan. y = elu(att @ Wh2).
__global__ __launch_bounds__(256) void gat_out_csr(
    const unsigned short* __restrict__ edges, const unsigned* __restrict__ cnt,
    const float* __restrict__ wh2, const float* __restrict__ consts,
    float* __restrict__ yhat) {
  const int lane = threadIdx.x & 63;
  const int i = blockIdx.x * 4 + (threadIdx.x >> 6);
  const unsigned n = cnt[i];
  const float Ai = consts[12] * wh2[i];
  const float oa1 = consts[13];
  float s = 0.f, t = 0.f;
  const unsigned short* er = edges + (size_t)i * 1024u;
  for (unsigned j = lane; j < n; j += 64) {
    const float wj = wh2[er[j]];
    float e = Ai + oa1 * wj;
    e = fmaxf(e, 0.2f * e);
    const float ww = expf(e);
    s += ww; t += ww * wj;
  }
  for (int o = 1; o < 64; o <<= 1) {
    s += __shfl_xor(s, o);
    t += __shfl_xor(t, o);
  }
  float v;
  if (n != 0) v = t / s;
  else {
    float a = 0.f;
    for (int k = lane; k < 4096; k += 64) a += wh2[k];
    for (int o = 1; o < 64; o <<= 1) a += __shfl_xor(a, o);
    v = a * (1.f / 4096.f);
  }
  if (lane == 0) yhat[i] = v > 0.f ? v : expm1f(v);
}

extern "C" void kernel_launch(void* const* d_in, const int* in_sizes, int n_in,
                              void* d_out, int out_size, void* d_ws, size_t ws_size,
                              hipStream_t stream) {
  const float* x      = (const float*)d_in[0];
  const float* eps    = (const float*)d_in[1];
  const void*  adj    = d_in[2];
  const float* enc_w1 = (const float*)d_in[3];
  const float* enc_b1 = (const float*)d_in[4];
  const float* enc_w2 = (const float*)d_in[5];
  const float* enc_b2 = (const float*)d_in[6];
  const float* enc_w3 = (const float*)d_in[7];
  const float* enc_b3 = (const float*)d_in[8];
  const float* enc_w4 = (const float*)d_in[9];
  const float* enc_b4 = (const float*)d_in[10];
  const float* dec_w1 = (const float*)d_in[11];
  const float* dec_b1 = (const float*)d_in[12];
  const float* dec_w2 = (const float*)d_in[13];
  const float* dec_b2 = (const float*)d_in[14];
  const float* dec_w3 = (const float*)d_in[15];
  const float* dec_b3 = (const float*)d_in[16];
  const float* gat_W  = (const float*)d_in[17];
  const float* gat_a  = (const float*)d_in[18];
  const float* out_W  = (const float*)d_in[19];
  const float* out_a  = (const float*)d_in[20];

  float* out    = (float*)d_out;
  float* xhat   = out;          // [0,4096)
  float* yhat   = out + 4096;   // [4096,8192)
  float* mu     = out + 8192;   // [8192,8704)
  float* logvar = out + 8704;   // [8704,9216)

  // ws layout: edges 8MB | cnt 16KB | float scratch
  unsigned short* edges = (unsigned short*)d_ws;
  unsigned* cnt = (unsigned*)((char*)d_ws + (size_t)4096 * 1024 * 2);
  float* F      = (float*)((char*)cnt + 4096 * sizeof(unsigned));
  float* h1     = F;            // 1024
  float* h2     = F + 1024;     // 1024
  float* h3     = F + 2048;     // 1024
  float* h4     = F + 3072;     // 1024
  float* wh2    = F + 4096;     // 4096
  float* consts = F + 8208;     // 14

  // Dispatch 1: conv->CSR (1024 blocks) + enc1 (1024 blocks) + prep (1).
  MegaP mp;
  mp.adj = adj; mp.edges = edges; mp.cnt = cnt;
  mp.w1 = enc_w1; mp.x = x; mp.b1 = enc_b1; mp.h1 = h1;
  mp.gw = gat_W; mp.ga = gat_a; mp.ow = out_W; mp.oa = out_a;
  mp.consts = consts;
  mega_kernel<<<2049, 256, 0, stream>>>(mp);

  // VAE chain (each stage depends fully on the previous).
  mv_kernel<ACT_RELU><<<1024, 256, 0, stream>>>(enc_w2, h1, enc_b2, h2, 1024);
  mulv_kernel<<<1024, 256, 0, stream>>>(enc_w3, enc_b3, enc_w4, enc_b4, h2, mu, logvar);
  dec1_kernel<<<1024, 256, 0, stream>>>(dec_w1, mu, logvar, eps, dec_b1, h3);
  mv_kernel<ACT_RELU><<<1024, 256, 0, stream>>>(dec_w2, h3, dec_b2, h4, 1024);
  mv_kernel<ACT_SIG ><<<4096, 256, 0, stream>>>(dec_w3, h4, dec_b3, xhat, 1024);

  // GAT (CSR + consts ready since dispatch 1, by stream order).
  gat_heads_csr<<<1024, 256, 0, stream>>>(edges, cnt, xhat, consts, wh2);
  gat_out_csr<<<1024, 256, 0, stream>>>(edges, cnt, wh2, consts, yhat);
}